// Round 7
// baseline (1287.715 us; speedup 1.0000x reference)
//
#include <hip/hip_runtime.h>
#include <hip/hip_bf16.h>
#include <hip/hip_fp16.h>

#define LEAK 0.2f
#define BCAP 4096   // edges per 128-node bucket; mean ~2176 for E/N=17, +40 sigma safe
#define NTILE 8     // src tiles per node adjacency (2MB of h16 per tile)
#define TSHIFT 13   // tile = src >> 13 ; requires N <= 65536
#define GRID_BLKS 1024  // exactly 4 blocks/CU x 256 CU; co-resident by resource math:
                        // __launch_bounds__(256,4) caps VGPR at 128, LDS 18.4KB -> 8/CU

typedef _Float16 half8  __attribute__((ext_vector_type(8)));
typedef _Float16 half4v __attribute__((ext_vector_type(4)));
typedef float    float4v __attribute__((ext_vector_type(4)));

struct MegaParams {
    const int* esrc; const int* edst;
    int* bars;                    // 4 software grid-barrier counters (pre-zeroed)
    int* gcnt; unsigned int* binned;
    int E; int ETOT; int NBK; int eb;
    const float* W0; const float* W1; const float* W2;
    _Float16* w16t;
    int2* offend; int* csr;
    const float* x;
    const float* asv[3]; const float* adv[3]; const float* bsv[3];
    const float* lw; const float* lb;
    float* logits;
    _Float16* h16a; _Float16* h16b; _Float16* bufA; _Float16* bufB;
    float* alsA; float* aldA; float* alsB; float* aldB;
    int N; int gemm_blocks; int ngrpE;
};

// ---------- software grid barrier (all GRID_BLKS blocks co-resident) ----------
// release-fence -> device-scope arrival -> acquire-poll -> acquire-fence.
// Counters are single-use per launch (pre-zeroed by host memset).
__device__ __forceinline__ void gridbar(int* bar) {
    __syncthreads();
    if (threadIdx.x == 0) {
        __threadfence();   // release: make my global writes visible device-wide
        __hip_atomic_fetch_add(bar, 1, __ATOMIC_RELEASE, __HIP_MEMORY_SCOPE_AGENT);
        const int n = (int)gridDim.x;
        while (__hip_atomic_load(bar, __ATOMIC_ACQUIRE, __HIP_MEMORY_SCOPE_AGENT) < n)
            __builtin_amdgcn_s_sleep(8);
        __threadfence();   // acquire: invalidate stale cached lines
    }
    __syncthreads();
}

// ---------- phase A: edge binning into fixed-capacity dst buckets ----------
__device__ void bin_chunk(int chunk, const MegaParams& P, char* smem) {
    int* lh    = (int*)smem;          // 2048B (NBK<=512)
    int* lbase = (int*)(smem + 2048); // 2048B
    int t = threadIdx.x;
    for (int b = t; b < P.NBK; b += 256) lh[b] = 0;
    __syncthreads();
    int base = chunk * 4096;
    unsigned int word[16]; int bb[16], rk[16];
    #pragma unroll
    for (int u = 0; u < 16; ++u) {
        int e = base + u * 256 + t;
        bb[u] = -1;
        if (e < P.ETOT) {
            int s, d;
            if (e < P.E) { s = P.esrc[e]; d = P.edst[e]; } else { s = d = e - P.E; }
            int b = d >> 7;
            bb[u] = b;
            rk[u] = atomicAdd(&lh[b], 1);
            word[u] = (unsigned int)s | ((unsigned int)(d & 127) << 17);
        }
    }
    __syncthreads();
    for (int b = t; b < P.NBK; b += 256) {
        int c = lh[b];
        lbase[b] = c ? atomicAdd(&P.gcnt[b], c) : 0;
    }
    __syncthreads();
    #pragma unroll
    for (int u = 0; u < 16; ++u)
        if (bb[u] >= 0)
            P.binned[(size_t)bb[u] * BCAP + lbase[bb[u]] + rk[u]] = word[u];
    __syncthreads();
}

// ---------- phase A: W -> fp16 transpose (12 tiles: 3 matrices x 4) ----------
__device__ void wtrans_tile(int bb, const MegaParams& P, char* smem) {
    typedef _Float16 (*TileT)[68];
    TileT tile = (TileT)smem;         // 64*68*2 = 8704B
    int t = threadIdx.x;
    int m = bb >> 2;
    int ti = (bb >> 1) & 1, tj = bb & 1;
    const float* src = (m == 0) ? P.W0 : (m == 1 ? P.W1 : P.W2);
    _Float16* dst = P.w16t + m * 16384;
    for (int idx = t; idx < 4096; idx += 256) {
        int r = idx >> 6, c = idx & 63;
        tile[r][c] = (_Float16)src[(ti * 64 + r) * 128 + tj * 64 + c];
    }
    __syncthreads();
    for (int idx = t; idx < 4096; idx += 256) {
        int c = idx >> 6, r = idx & 63;
        dst[(tj * 64 + c) * 128 + ti * 64 + r] = tile[r][c];
    }
    __syncthreads();
}

// ---------- phase B: per-bucket CSR finalize (src-tile-grouped) ----------
__device__ void scatter2_body(int b, const MegaParams& P, char* smem) {
    int* deg  = (int*)smem;            // 4096B
    int* lcur = (int*)(smem + 4096);   // 4096B
    int* wt   = (int*)(smem + 8192);   // 8B
    int t = threadIdx.x;
    int n0 = b << 7;
    for (int i = t; i < 128 * NTILE; i += 256) deg[i] = 0;
    __syncthreads();
    int beg = b * BCAP, end = beg + P.gcnt[b];
    for (int i = beg + t; i < end; i += 256) {
        unsigned int u = P.binned[i];
        atomicAdd(&deg[(u >> 17) * NTILE + ((u & 0x1FFFF) >> TSHIFT)], 1);
    }
    __syncthreads();
    int v = 0, x = 0;
    if (t < 128) {
        #pragma unroll
        for (int k = 0; k < NTILE; ++k) v += deg[t * NTILE + k];
        x = v;
        int lane = t & 63;
        #pragma unroll
        for (int o = 1; o < 64; o <<= 1) {
            int y = __shfl_up(x, o);
            if (lane >= o) x += y;
        }
        if (lane == 63) wt[t >> 6] = x;
    }
    __syncthreads();
    if (t < 128) {
        int excl = x - v + ((t >= 64) ? wt[0] : 0) + beg;
        int run = excl;
        #pragma unroll
        for (int k = 0; k < NTILE; ++k) {
            lcur[t * NTILE + k] = run;
            run += deg[t * NTILE + k];
        }
        int node = n0 + t;
        if (node < P.N) P.offend[node] = make_int2(excl, excl + v);
    }
    __syncthreads();
    for (int i = beg + t; i < end; i += 256) {
        unsigned int u = P.binned[i];
        int pos = atomicAdd(&lcur[(u >> 17) * NTILE + ((u & 0x1FFFF) >> TSHIFT)], 1);
        P.csr[pos] = (int)(u & 0x1FFFF);
    }
    __syncthreads();
}

// ---------- MFMA GEMM tile + fused attention logits ----------
// X32 != nullptr: stage fp32 rows from global. X32 == nullptr: As pre-filled
// by the fused aggregate (phase C/D). 16x16x32_f16 lane maps (m89-verified).
__device__ void gemm_tile(int tile, const float* X32,
                          const _Float16* __restrict__ WhT,
                          const float* __restrict__ a_src,
                          const float* __restrict__ a_dst,
                          _Float16* __restrict__ Hout,
                          float* __restrict__ alsrc, float* __restrict__ aldst,
                          int N, char* smem) {
    typedef _Float16 (*AsT)[136];
    AsT As = (AsT)smem;                              // 17408B
    float (*sS)[2] = (float(*)[2])(smem + 17408);    // 512B
    float (*sD)[2] = (float(*)[2])(smem + 17920);    // 512B
    const int t = threadIdx.x;
    const int lane = t & 63, w = t >> 6;
    const int block_row = tile * 64;

    if (t < 128) { sS[t >> 1][t & 1] = 0.f; sD[t >> 1][t & 1] = 0.f; }

    if (X32) {
        #pragma unroll
        for (int it = 0; it < 8; ++it) {
            int i = t + 256 * it;
            int row = i >> 5, c4 = i & 31;
            int gr = block_row + row;
            float4 xv = make_float4(0.f, 0.f, 0.f, 0.f);
            if (gr < N) xv = *(const float4*)(X32 + (size_t)gr * 128 + c4 * 4);
            half4v hv;
            hv[0] = (_Float16)xv.x; hv[1] = (_Float16)xv.y;
            hv[2] = (_Float16)xv.z; hv[3] = (_Float16)xv.w;
            *(half4v*)(&As[row][c4 * 4]) = hv;
        }
    }

    const int l15 = lane & 15, kq = (lane >> 4) * 8;
    half8 bf[2][4];
    #pragma unroll
    for (int ntl = 0; ntl < 2; ++ntl) {
        int n0 = (w * 2 + ntl) * 16 + l15;
        #pragma unroll
        for (int kt = 0; kt < 4; ++kt)
            bf[ntl][kt] = *(const half8*)(WhT + (size_t)n0 * 128 + kt * 32 + kq);
    }
    __syncthreads();   // As staged (or agg-filled) + sS/sD zeroed

    float4v acc[4][2];
    #pragma unroll
    for (int mt = 0; mt < 4; ++mt)
        #pragma unroll
        for (int ntl = 0; ntl < 2; ++ntl)
            acc[mt][ntl] = (float4v){0.f, 0.f, 0.f, 0.f};

    #pragma unroll
    for (int kt = 0; kt < 4; ++kt) {
        half8 a[4];
        #pragma unroll
        for (int mt = 0; mt < 4; ++mt)
            a[mt] = *(const half8*)(&As[mt * 16 + l15][kt * 32 + kq]);
        #pragma unroll
        for (int mt = 0; mt < 4; ++mt)
            #pragma unroll
            for (int ntl = 0; ntl < 2; ++ntl)
                acc[mt][ntl] = __builtin_amdgcn_mfma_f32_16x16x32_f16(
                    a[mt], bf[ntl][kt], acc[mt][ntl], 0, 0, 0);
    }

    #pragma unroll
    for (int mt = 0; mt < 4; ++mt) {
        int r0 = block_row + mt * 16 + (lane >> 4) * 4;
        #pragma unroll
        for (int ntl = 0; ntl < 2; ++ntl) {
            int col = (w * 2 + ntl) * 16 + l15;
            #pragma unroll
            for (int reg = 0; reg < 4; ++reg) {
                int r = r0 + reg;
                if (r < N) Hout[(size_t)r * 128 + col] = (_Float16)acc[mt][ntl][reg];
            }
        }
    }

    // fused attention logits: wave covers cols [w*32, w*32+32) -> head = w>>1
    {
        int c0 = w * 32 + l15, c1 = c0 + 16;
        float as0 = a_src[c0], as1 = a_src[c1];
        float ad0 = a_dst[c0], ad1 = a_dst[c1];
        int head = w >> 1;
        #pragma unroll
        for (int mt = 0; mt < 4; ++mt) {
            #pragma unroll
            for (int reg = 0; reg < 4; ++reg) {
                float ps = (float)acc[mt][0][reg] * as0 + (float)acc[mt][1][reg] * as1;
                float pd = (float)acc[mt][0][reg] * ad0 + (float)acc[mt][1][reg] * ad1;
                #pragma unroll
                for (int o = 1; o < 16; o <<= 1) {
                    ps += __shfl_xor(ps, o);
                    pd += __shfl_xor(pd, o);
                }
                if (l15 == 0) {
                    int row = mt * 16 + (lane >> 4) * 4 + reg;
                    atomicAdd(&sS[row][head], ps);
                    atomicAdd(&sD[row][head], pd);
                }
            }
        }
    }
    __syncthreads();
    if (t < 128) {
        int row = t >> 1, head = t & 1;
        int gr = block_row + row;
        if (gr < N) {
            alsrc[gr * 2 + head] = sS[row][head];
            aldst[gr * 2 + head] = sD[row][head];
        }
    }
    __syncthreads();   // protect smem reuse by the next grid-stride iteration
}

// ---------- register softmax-aggregate for 2 nodes per wave (R2-proven) ----
__device__ __forceinline__ bool agg2(const _Float16* __restrict__ H16,
        const float* __restrict__ alsrc, const float* __restrict__ aldst,
        const int2* __restrict__ offend, const int* __restrict__ csr,
        int node, int N, float* __restrict__ vout) {
    const int lane = threadIdx.x & 63;
    const int half = lane >> 5, hl = lane & 31;
    const int p = hl & 15, q = hl >> 4;
    const bool head0 = p < 8;
    const _Float16* hbase = H16 + p * 8;
    const int hb = half << 5;
    bool active = node < N;
    int nodeC = active ? node : (N - 1);
    int2 oe = offend[nodeC];
    int beg = oe.x;
    int end = active ? oe.y : beg;
    float2 adv = *(const float2*)(aldst + (size_t)nodeC * 2);
    float ad0 = adv.x, ad1 = adv.y;

    float acc[8];
    #pragma unroll
    for (int k = 0; k < 8; ++k) acc[k] = 0.f;
    float dsum = 0.f;

    for (int base = beg; base < end; base += 32) {
        int i = base + hl;
        int s = 0; float w0 = 0.f, w1 = 0.f;
        if (i < end) {
            s = csr[i];
            float2 al = *(const float2*)(&alsrc[s * 2]);
            float e0 = al.x + ad0; e0 = e0 > 0.f ? e0 : LEAK * e0;
            float e1 = al.y + ad1; e1 = e1 > 0.f ? e1 : LEAK * e1;
            w0 = __expf(e0); w1 = __expf(e1);
        }
        int cnt = min(32, end - base);
        int iters = (cnt + 1) >> 1;
        int jj = 0;
        for (; jj + 4 <= iters; jj += 4) {
            int sl0 = hb + (jj << 1) + q;
            int sj0 = __shfl(s, sl0), sj1 = __shfl(s, sl0 + 2);
            int sj2 = __shfl(s, sl0 + 4), sj3 = __shfl(s, sl0 + 6);
            float w00 = __shfl(w0, sl0),     w10 = __shfl(w1, sl0);
            float w01 = __shfl(w0, sl0 + 2), w11 = __shfl(w1, sl0 + 2);
            float w02 = __shfl(w0, sl0 + 4), w12 = __shfl(w1, sl0 + 4);
            float w03 = __shfl(w0, sl0 + 6), w13 = __shfl(w1, sl0 + 6);
            float ws0 = head0 ? w00 : w10;
            float ws1 = head0 ? w01 : w11;
            float ws2 = head0 ? w02 : w12;
            float ws3 = head0 ? w03 : w13;
            uint4 r0 = *(const uint4*)(hbase + (size_t)sj0 * 128);
            uint4 r1 = *(const uint4*)(hbase + (size_t)sj1 * 128);
            uint4 r2 = *(const uint4*)(hbase + (size_t)sj2 * 128);
            uint4 r3 = *(const uint4*)(hbase + (size_t)sj3 * 128);
            const _Float16* h0 = (const _Float16*)&r0;
            const _Float16* h1 = (const _Float16*)&r1;
            const _Float16* h2 = (const _Float16*)&r2;
            const _Float16* h3 = (const _Float16*)&r3;
            #pragma unroll
            for (int k = 0; k < 8; ++k) acc[k] += ws0 * (float)h0[k];
            #pragma unroll
            for (int k = 0; k < 8; ++k) acc[k] += ws1 * (float)h1[k];
            #pragma unroll
            for (int k = 0; k < 8; ++k) acc[k] += ws2 * (float)h2[k];
            #pragma unroll
            for (int k = 0; k < 8; ++k) acc[k] += ws3 * (float)h3[k];
            dsum += (ws0 + ws1) + (ws2 + ws3);
        }
        for (; jj + 2 <= iters; jj += 2) {
            int sl0 = hb + (jj << 1) + q;
            int sj0 = __shfl(s, sl0), sj1 = __shfl(s, sl0 + 2);
            float w00 = __shfl(w0, sl0),     w10 = __shfl(w1, sl0);
            float w01 = __shfl(w0, sl0 + 2), w11 = __shfl(w1, sl0 + 2);
            float ws0 = head0 ? w00 : w10;
            float ws1 = head0 ? w01 : w11;
            uint4 r0 = *(const uint4*)(hbase + (size_t)sj0 * 128);
            uint4 r1 = *(const uint4*)(hbase + (size_t)sj1 * 128);
            const _Float16* h0 = (const _Float16*)&r0;
            const _Float16* h1 = (const _Float16*)&r1;
            #pragma unroll
            for (int k = 0; k < 8; ++k) acc[k] += ws0 * (float)h0[k];
            #pragma unroll
            for (int k = 0; k < 8; ++k) acc[k] += ws1 * (float)h1[k];
            dsum += ws0 + ws1;
        }
        if (jj < iters) {
            int sl = hb + (jj << 1) + q;
            int   sj = __shfl(s,  sl);
            float wa = __shfl(w0, sl);
            float wb = __shfl(w1, sl);
            float ws = head0 ? wa : wb;
            uint4 raw = *(const uint4*)(hbase + (size_t)sj * 128);
            const _Float16* h = (const _Float16*)&raw;
            #pragma unroll
            for (int k = 0; k < 8; ++k) acc[k] += ws * (float)h[k];
            dsum += ws;
        }
    }

    // merge the two q-groups within each half (NOT across halves!)
    #pragma unroll
    for (int k = 0; k < 8; ++k) acc[k] += __shfl_xor(acc[k], 16);
    dsum += __shfl_xor(dsum, 16);

    float inv = 1.f / dsum;
    #pragma unroll
    for (int k = 0; k < 8; ++k) vout[k] = acc[k] * inv;
    return (q == 0) && active;
}

// ---------- phase C/D: fused aggregate(64 nodes) + next-layer GEMM ----------
__device__ void agg_gemm_tile(int tile,
        const _Float16* Hin, const float* alsrcL, const float* aldstL,
        const float* biasL, const _Float16* prev, _Float16* Res,
        const _Float16* WhT, const float* a_src, const float* a_dst,
        _Float16* Hout, float* alsrcO, float* aldstO,
        const MegaParams& P, char* smem) {
    typedef _Float16 (*AsT)[136];
    AsT As = (AsT)smem;
    const int t = threadIdx.x;
    const int lane = t & 63, w = t >> 6;
    const int block_row = tile * 64;
    const int half = lane >> 5, hl = lane & 31, p = hl & 15;

    for (int j = 0; j < 8; ++j) {
        int node = block_row + w * 16 + j * 2 + half;
        float v[8];
        bool valid = agg2(Hin, alsrcL, aldstL, P.offend, P.csr, node, P.N, v);
        if (valid) {
            int c0 = p * 8;
            #pragma unroll
            for (int k = 0; k < 8; ++k) v[k] += biasL[c0 + k];
            if (prev) {
                half8 pv = *(const half8*)(prev + (size_t)node * 128 + c0);
                #pragma unroll
                for (int k = 0; k < 8; ++k) v[k] += (float)pv[k];
            }
            #pragma unroll
            for (int k = 0; k < 8; ++k) v[k] = v[k] > 0.f ? v[k] : LEAK * v[k];
            half8 ov;
            #pragma unroll
            for (int k = 0; k < 8; ++k) ov[k] = (_Float16)v[k];
            *(half8*)(&As[node - block_row][c0]) = ov;
            *(half8*)(Res + (size_t)node * 128 + c0) = ov;
        }
    }
    // gemm_tile syncs before reading As (covers the agg writes above)
    gemm_tile(tile, nullptr, WhT, a_src, a_dst, Hout, alsrcO, aldstO, P.N, smem);
}

// ---------- the mega-kernel (normal launch, software grid barriers) ----------
__global__ __launch_bounds__(256, 4) void k_mega(MegaParams P) {
    __shared__ __align__(16) char smem[18448];
    const int G = (int)gridDim.x;
    const int bid = (int)blockIdx.x;

    // Phase A: edge binning + W transpose
    for (int it = bid; it < P.eb + 12; it += G) {
        if (it < P.eb) bin_chunk(it, P, smem);
        else           wtrans_tile(it - P.eb, P, smem);
    }
    gridbar(P.bars + 0);

    // Phase B: CSR finalize (NBK items) || GEMM layer 1 (gemm_blocks items)
    for (int it = bid; it < P.NBK + P.gemm_blocks; it += G) {
        if (it < P.NBK) scatter2_body(it, P, smem);
        else gemm_tile(it - P.NBK, P.x, P.w16t, P.asv[0], P.adv[0],
                       P.h16a, P.alsA, P.aldA, P.N, smem);
    }
    gridbar(P.bars + 1);

    // Phase C: fused agg layer1 (bias only) + GEMM layer2
    for (int it = bid; it < P.gemm_blocks; it += G)
        agg_gemm_tile(it, P.h16a, P.alsA, P.aldA, P.bsv[0], nullptr, P.bufA,
                      P.w16t + 16384, P.asv[1], P.adv[1],
                      P.h16b, P.alsB, P.aldB, P, smem);
    gridbar(P.bars + 2);

    // Phase D: fused agg layer2 (prev=bufA) + GEMM layer3
    for (int it = bid; it < P.gemm_blocks; it += G)
        agg_gemm_tile(it, P.h16b, P.alsB, P.aldB, P.bsv[1], P.bufA, P.bufB,
                      P.w16t + 32768, P.asv[2], P.adv[2],
                      P.h16a, P.alsA, P.aldA, P, smem);
    gridbar(P.bars + 3);

    // Phase E: agg layer3 (prev=bufB) + fused final linear -> logits
    {
        const int t = threadIdx.x;
        const int w = t >> 6, lane = t & 63;
        const int half = lane >> 5, hl = lane & 31, p = hl & 15;
        for (int grp = bid; grp < P.ngrpE; grp += G) {
            int node = grp * 8 + w * 2 + half;
            float v[8];
            bool valid = agg2(P.h16a, P.alsA, P.aldA, P.offend, P.csr, node, P.N, v);
            if (valid) {
                int c0 = p * 8;
                #pragma unroll
                for (int k = 0; k < 8; ++k) v[k] += P.bsv[2][c0 + k];
                half8 pv = *(const half8*)(P.bufB + (size_t)node * 128 + c0);
                #pragma unroll
                for (int k = 0; k < 8; ++k) v[k] += (float)pv[k];
                #pragma unroll
                for (int k = 0; k < 8; ++k) v[k] = v[k] > 0.f ? v[k] : LEAK * v[k];
                float partial = 0.f;
                #pragma unroll
                for (int k = 0; k < 8; ++k) partial += v[k] * P.lw[c0 + k];
                partial += __shfl_xor(partial, 1);
                partial += __shfl_xor(partial, 2);
                partial += __shfl_xor(partial, 4);
                partial += __shfl_xor(partial, 8);
                if (hl == 0) P.logits[node] = partial + P.lb[0];
            }
        }
    }
}

// ================= launch =================

extern "C" void kernel_launch(void* const* d_in, const int* in_sizes, int n_in,
                              void* d_out, int out_size, void* d_ws, size_t ws_size,
                              hipStream_t stream) {
    const float* x    = (const float*)d_in[0];
    const int*   edge = (const int*)d_in[1];
    const float* W[3]  = {(const float*)d_in[2], (const float*)d_in[6], (const float*)d_in[10]};
    const float* as[3] = {(const float*)d_in[3], (const float*)d_in[7], (const float*)d_in[11]};
    const float* ad[3] = {(const float*)d_in[4], (const float*)d_in[8], (const float*)d_in[12]};
    const float* bs[3] = {(const float*)d_in[5], (const float*)d_in[9], (const float*)d_in[13]};
    const float* lw = (const float*)d_in[14];
    const float* lb = (const float*)d_in[15];

    const int N    = in_sizes[0] / 128;
    const int E    = in_sizes[1] / 2;
    const int ETOT = E + N;
    const int NBK  = (N + 127) >> 7;   // requires N <= 65536 (here N = 50000)

    char* base = (char*)d_ws;
    size_t o = 0;
    auto carve = [&](size_t bytes) {
        char* p = base + o;
        o = (o + bytes + 255) & ~(size_t)255;
        return p;
    };
    int*      bars   = (int*)     carve(64);            // 4 barrier counters (256B slot)
    int*      gcnt   = (int*)     carve((size_t)NBK * 4);
    int2*     offend = (int2*)    carve((size_t)N * 8);
    unsigned* binned = (unsigned*)carve((size_t)NBK * BCAP * 4);
    int*      csr    = (int*)     carve((size_t)NBK * BCAP * 4);
    float*    alsA   = (float*)   carve((size_t)N * 2 * 4);
    float*    aldA   = (float*)   carve((size_t)N * 2 * 4);
    float*    alsB   = (float*)   carve((size_t)N * 2 * 4);
    float*    aldB   = (float*)   carve((size_t)N * 2 * 4);
    _Float16* h16a   = (_Float16*)carve((size_t)N * 128 * 2);
    _Float16* h16b   = (_Float16*)carve((size_t)N * 128 * 2);
    _Float16* bufA   = (_Float16*)carve((size_t)N * 128 * 2);
    _Float16* bufB   = (_Float16*)carve((size_t)N * 128 * 2);
    _Float16* w16t   = (_Float16*)carve((size_t)3 * 16384 * 2);
    (void)ws_size; (void)n_in; (void)out_size;

    // zero barrier counters + bucket counters in one memset (adjacent carves)
    hipMemsetAsync(bars, 0, 256 + (size_t)NBK * 4, stream);

    MegaParams P;
    P.esrc = edge; P.edst = edge + E;
    P.bars = bars;
    P.gcnt = gcnt; P.binned = binned;
    P.E = E; P.ETOT = ETOT; P.NBK = NBK;
    P.eb = (ETOT + 4095) / 4096;
    P.W0 = W[0]; P.W1 = W[1]; P.W2 = W[2];
    P.w16t = w16t;
    P.offend = offend; P.csr = csr;
    P.x = x;
    for (int i = 0; i < 3; ++i) { P.asv[i] = as[i]; P.adv[i] = ad[i]; P.bsv[i] = bs[i]; }
    P.lw = lw; P.lb = lb;
    P.logits = (float*)d_out;
    P.h16a = h16a; P.h16b = h16b; P.bufA = bufA; P.bufB = bufB;
    P.alsA = alsA; P.aldA = aldA; P.alsB = alsB; P.aldB = aldB;
    P.N = N;
    P.gemm_blocks = (N + 63) / 64;
    P.ngrpE = (N + 7) / 8;

    k_mega<<<GRID_BLKS, 256, 0, stream>>>(P);
}

// Round 9
// 647.607 us; speedup vs baseline: 1.9884x; 1.9884x over previous
//
#include <hip/hip_runtime.h>
#include <hip/hip_bf16.h>
#include <hip/hip_fp16.h>

#define LEAK 0.2f
#define BCAP 4096   // edges per 128-node bucket; mean ~2176 for E/N=17, +40 sigma safe
#define NTILE 8     // src tiles per node adjacency (2MB of h16 per tile)
#define TSHIFT 13   // tile = src >> 13 ; requires N <= 65536
#define GRID_BLKS 1024  // exactly 4 blocks/CU x 256 CU; co-resident by resource math:
                        // __launch_bounds__(256,4) caps VGPR at 128, LDS 18.4KB -> 8/CU

typedef _Float16 half8  __attribute__((ext_vector_type(8)));
typedef _Float16 half4v __attribute__((ext_vector_type(4)));
typedef float    float4v __attribute__((ext_vector_type(4)));

struct MegaParams {
    const int* esrc; const int* edst;
    int* bars;                    // 4 software grid-barrier counters (pre-zeroed)
    int* gcnt; unsigned int* binned;
    int E; int ETOT; int NBK; int eb;
    const float* W0; const float* W1; const float* W2;
    _Float16* w16t;
    int2* offend; int* csr;
    const float* x;
    const float* asv[3]; const float* adv[3]; const float* bsv[3];
    const float* lw; const float* lb;
    float* logits;
    _Float16* h16a; _Float16* h16b; _Float16* bufA; _Float16* bufB;
    float* alsA; float* aldA; float* alsB; float* aldB;
    int N; int gemm_blocks; int ngrpE;
};

// ---------- software grid barrier (all GRID_BLKS blocks co-resident) ----------
// R7 lesson: an agent-scope ACQUIRE load in the poll loop invalidates the whole
// per-XCD L2 EVERY iteration -> all 8 L2s continuously wiped -> gather rate
// collapsed 10x (346 GB/s, VALUBusy 4%). Fix: RELAXED polling (agent-scope
// atomic loads bypass L2 to the coherence point, so arrivals are still seen,
// but nothing is invalidated), then exactly ONE acquire (fence + acquire load)
// after the poll exits. R8 fix: __hip_atomic_thread_fence doesn't exist; use
// __builtin_amdgcn_fence(order, "agent").
__device__ __forceinline__ void gridbar(int* bar) {
    __syncthreads();
    if (threadIdx.x == 0) {
        // RELEASE arrival: writes back this block's dirty lines once, then bumps.
        __hip_atomic_fetch_add(bar, 1, __ATOMIC_RELEASE, __HIP_MEMORY_SCOPE_AGENT);
        const int n = (int)gridDim.x;
        while (__hip_atomic_load(bar, __ATOMIC_RELAXED, __HIP_MEMORY_SCOPE_AGENT) < n)
            __builtin_amdgcn_s_sleep(32);
        // ONE acquire: invalidate stale L2 lines exactly once per barrier.
        (void)__hip_atomic_load(bar, __ATOMIC_ACQUIRE, __HIP_MEMORY_SCOPE_AGENT);
        __builtin_amdgcn_fence(__ATOMIC_ACQUIRE, "agent");
    }
    __syncthreads();
}

// ---------- phase A: edge binning into fixed-capacity dst buckets ----------
__device__ void bin_chunk(int chunk, const MegaParams& P, char* smem) {
    int* lh    = (int*)smem;          // 2048B (NBK<=512)
    int* lbase = (int*)(smem + 2048); // 2048B
    int t = threadIdx.x;
    for (int b = t; b < P.NBK; b += 256) lh[b] = 0;
    __syncthreads();
    int base = chunk * 4096;
    unsigned int word[16]; int bb[16], rk[16];
    #pragma unroll
    for (int u = 0; u < 16; ++u) {
        int e = base + u * 256 + t;
        bb[u] = -1;
        if (e < P.ETOT) {
            int s, d;
            if (e < P.E) { s = P.esrc[e]; d = P.edst[e]; } else { s = d = e - P.E; }
            int b = d >> 7;
            bb[u] = b;
            rk[u] = atomicAdd(&lh[b], 1);
            word[u] = (unsigned int)s | ((unsigned int)(d & 127) << 17);
        }
    }
    __syncthreads();
    for (int b = t; b < P.NBK; b += 256) {
        int c = lh[b];
        lbase[b] = c ? atomicAdd(&P.gcnt[b], c) : 0;
    }
    __syncthreads();
    #pragma unroll
    for (int u = 0; u < 16; ++u)
        if (bb[u] >= 0)
            P.binned[(size_t)bb[u] * BCAP + lbase[bb[u]] + rk[u]] = word[u];
    __syncthreads();
}

// ---------- phase A: W -> fp16 transpose (12 tiles: 3 matrices x 4) ----------
__device__ void wtrans_tile(int bb, const MegaParams& P, char* smem) {
    typedef _Float16 (*TileT)[68];
    TileT tile = (TileT)smem;         // 64*68*2 = 8704B
    int t = threadIdx.x;
    int m = bb >> 2;
    int ti = (bb >> 1) & 1, tj = bb & 1;
    const float* src = (m == 0) ? P.W0 : (m == 1 ? P.W1 : P.W2);
    _Float16* dst = P.w16t + m * 16384;
    for (int idx = t; idx < 4096; idx += 256) {
        int r = idx >> 6, c = idx & 63;
        tile[r][c] = (_Float16)src[(ti * 64 + r) * 128 + tj * 64 + c];
    }
    __syncthreads();
    for (int idx = t; idx < 4096; idx += 256) {
        int c = idx >> 6, r = idx & 63;
        dst[(tj * 64 + c) * 128 + ti * 64 + r] = tile[r][c];
    }
    __syncthreads();
}

// ---------- phase B: per-bucket CSR finalize (src-tile-grouped) ----------
__device__ void scatter2_body(int b, const MegaParams& P, char* smem) {
    int* deg  = (int*)smem;            // 4096B
    int* lcur = (int*)(smem + 4096);   // 4096B
    int* wt   = (int*)(smem + 8192);   // 8B
    int t = threadIdx.x;
    int n0 = b << 7;
    for (int i = t; i < 128 * NTILE; i += 256) deg[i] = 0;
    __syncthreads();
    int beg = b * BCAP, end = beg + P.gcnt[b];
    for (int i = beg + t; i < end; i += 256) {
        unsigned int u = P.binned[i];
        atomicAdd(&deg[(u >> 17) * NTILE + ((u & 0x1FFFF) >> TSHIFT)], 1);
    }
    __syncthreads();
    int v = 0, x = 0;
    if (t < 128) {
        #pragma unroll
        for (int k = 0; k < NTILE; ++k) v += deg[t * NTILE + k];
        x = v;
        int lane = t & 63;
        #pragma unroll
        for (int o = 1; o < 64; o <<= 1) {
            int y = __shfl_up(x, o);
            if (lane >= o) x += y;
        }
        if (lane == 63) wt[t >> 6] = x;
    }
    __syncthreads();
    if (t < 128) {
        int excl = x - v + ((t >= 64) ? wt[0] : 0) + beg;
        int run = excl;
        #pragma unroll
        for (int k = 0; k < NTILE; ++k) {
            lcur[t * NTILE + k] = run;
            run += deg[t * NTILE + k];
        }
        int node = n0 + t;
        if (node < P.N) P.offend[node] = make_int2(excl, excl + v);
    }
    __syncthreads();
    for (int i = beg + t; i < end; i += 256) {
        unsigned int u = P.binned[i];
        int pos = atomicAdd(&lcur[(u >> 17) * NTILE + ((u & 0x1FFFF) >> TSHIFT)], 1);
        P.csr[pos] = (int)(u & 0x1FFFF);
    }
    __syncthreads();
}

// ---------- MFMA GEMM tile + fused attention logits ----------
// X32 != nullptr: stage fp32 rows from global. X32 == nullptr: As pre-filled
// by the fused aggregate (phase C/D). 16x16x32_f16 lane maps (m89-verified).
__device__ void gemm_tile(int tile, const float* X32,
                          const _Float16* __restrict__ WhT,
                          const float* __restrict__ a_src,
                          const float* __restrict__ a_dst,
                          _Float16* __restrict__ Hout,
                          float* __restrict__ alsrc, float* __restrict__ aldst,
                          int N, char* smem) {
    typedef _Float16 (*AsT)[136];
    AsT As = (AsT)smem;                              // 17408B
    float (*sS)[2] = (float(*)[2])(smem + 17408);    // 512B
    float (*sD)[2] = (float(*)[2])(smem + 17920);    // 512B
    const int t = threadIdx.x;
    const int lane = t & 63, w = t >> 6;
    const int block_row = tile * 64;

    if (t < 128) { sS[t >> 1][t & 1] = 0.f; sD[t >> 1][t & 1] = 0.f; }

    if (X32) {
        #pragma unroll
        for (int it = 0; it < 8; ++it) {
            int i = t + 256 * it;
            int row = i >> 5, c4 = i & 31;
            int gr = block_row + row;
            float4 xv = make_float4(0.f, 0.f, 0.f, 0.f);
            if (gr < N) xv = *(const float4*)(X32 + (size_t)gr * 128 + c4 * 4);
            half4v hv;
            hv[0] = (_Float16)xv.x; hv[1] = (_Float16)xv.y;
            hv[2] = (_Float16)xv.z; hv[3] = (_Float16)xv.w;
            *(half4v*)(&As[row][c4 * 4]) = hv;
        }
    }

    const int l15 = lane & 15, kq = (lane >> 4) * 8;
    half8 bf[2][4];
    #pragma unroll
    for (int ntl = 0; ntl < 2; ++ntl) {
        int n0 = (w * 2 + ntl) * 16 + l15;
        #pragma unroll
        for (int kt = 0; kt < 4; ++kt)
            bf[ntl][kt] = *(const half8*)(WhT + (size_t)n0 * 128 + kt * 32 + kq);
    }
    __syncthreads();   // As staged (or agg-filled) + sS/sD zeroed

    float4v acc[4][2];
    #pragma unroll
    for (int mt = 0; mt < 4; ++mt)
        #pragma unroll
        for (int ntl = 0; ntl < 2; ++ntl)
            acc[mt][ntl] = (float4v){0.f, 0.f, 0.f, 0.f};

    #pragma unroll
    for (int kt = 0; kt < 4; ++kt) {
        half8 a[4];
        #pragma unroll
        for (int mt = 0; mt < 4; ++mt)
            a[mt] = *(const half8*)(&As[mt * 16 + l15][kt * 32 + kq]);
        #pragma unroll
        for (int mt = 0; mt < 4; ++mt)
            #pragma unroll
            for (int ntl = 0; ntl < 2; ++ntl)
                acc[mt][ntl] = __builtin_amdgcn_mfma_f32_16x16x32_f16(
                    a[mt], bf[ntl][kt], acc[mt][ntl], 0, 0, 0);
    }

    #pragma unroll
    for (int mt = 0; mt < 4; ++mt) {
        int r0 = block_row + mt * 16 + (lane >> 4) * 4;
        #pragma unroll
        for (int ntl = 0; ntl < 2; ++ntl) {
            int col = (w * 2 + ntl) * 16 + l15;
            #pragma unroll
            for (int reg = 0; reg < 4; ++reg) {
                int r = r0 + reg;
                if (r < N) Hout[(size_t)r * 128 + col] = (_Float16)acc[mt][ntl][reg];
            }
        }
    }

    // fused attention logits: wave covers cols [w*32, w*32+32) -> head = w>>1
    {
        int c0 = w * 32 + l15, c1 = c0 + 16;
        float as0 = a_src[c0], as1 = a_src[c1];
        float ad0 = a_dst[c0], ad1 = a_dst[c1];
        int head = w >> 1;
        #pragma unroll
        for (int mt = 0; mt < 4; ++mt) {
            #pragma unroll
            for (int reg = 0; reg < 4; ++reg) {
                float ps = (float)acc[mt][0][reg] * as0 + (float)acc[mt][1][reg] * as1;
                float pd = (float)acc[mt][0][reg] * ad0 + (float)acc[mt][1][reg] * ad1;
                #pragma unroll
                for (int o = 1; o < 16; o <<= 1) {
                    ps += __shfl_xor(ps, o);
                    pd += __shfl_xor(pd, o);
                }
                if (l15 == 0) {
                    int row = mt * 16 + (lane >> 4) * 4 + reg;
                    atomicAdd(&sS[row][head], ps);
                    atomicAdd(&sD[row][head], pd);
                }
            }
        }
    }
    __syncthreads();
    if (t < 128) {
        int row = t >> 1, head = t & 1;
        int gr = block_row + row;
        if (gr < N) {
            alsrc[gr * 2 + head] = sS[row][head];
            aldst[gr * 2 + head] = sD[row][head];
        }
    }
    __syncthreads();   // protect smem reuse by the next grid-stride iteration
}

// ---------- register softmax-aggregate for 2 nodes per wave (R2-proven) ----
__device__ __forceinline__ bool agg2(const _Float16* __restrict__ H16,
        const float* __restrict__ alsrc, const float* __restrict__ aldst,
        const int2* __restrict__ offend, const int* __restrict__ csr,
        int node, int N, float* __restrict__ vout) {
    const int lane = threadIdx.x & 63;
    const int half = lane >> 5, hl = lane & 31;
    const int p = hl & 15, q = hl >> 4;
    const bool head0 = p < 8;
    const _Float16* hbase = H16 + p * 8;
    const int hb = half << 5;
    bool active = node < N;
    int nodeC = active ? node : (N - 1);
    int2 oe = offend[nodeC];
    int beg = oe.x;
    int end = active ? oe.y : beg;
    float2 adv = *(const float2*)(aldst + (size_t)nodeC * 2);
    float ad0 = adv.x, ad1 = adv.y;

    float acc[8];
    #pragma unroll
    for (int k = 0; k < 8; ++k) acc[k] = 0.f;
    float dsum = 0.f;

    for (int base = beg; base < end; base += 32) {
        int i = base + hl;
        int s = 0; float w0 = 0.f, w1 = 0.f;
        if (i < end) {
            s = csr[i];
            float2 al = *(const float2*)(&alsrc[s * 2]);
            float e0 = al.x + ad0; e0 = e0 > 0.f ? e0 : LEAK * e0;
            float e1 = al.y + ad1; e1 = e1 > 0.f ? e1 : LEAK * e1;
            w0 = __expf(e0); w1 = __expf(e1);
        }
        int cnt = min(32, end - base);
        int iters = (cnt + 1) >> 1;
        int jj = 0;
        for (; jj + 4 <= iters; jj += 4) {
            int sl0 = hb + (jj << 1) + q;
            int sj0 = __shfl(s, sl0), sj1 = __shfl(s, sl0 + 2);
            int sj2 = __shfl(s, sl0 + 4), sj3 = __shfl(s, sl0 + 6);
            float w00 = __shfl(w0, sl0),     w10 = __shfl(w1, sl0);
            float w01 = __shfl(w0, sl0 + 2), w11 = __shfl(w1, sl0 + 2);
            float w02 = __shfl(w0, sl0 + 4), w12 = __shfl(w1, sl0 + 4);
            float w03 = __shfl(w0, sl0 + 6), w13 = __shfl(w1, sl0 + 6);
            float ws0 = head0 ? w00 : w10;
            float ws1 = head0 ? w01 : w11;
            float ws2 = head0 ? w02 : w12;
            float ws3 = head0 ? w03 : w13;
            uint4 r0 = *(const uint4*)(hbase + (size_t)sj0 * 128);
            uint4 r1 = *(const uint4*)(hbase + (size_t)sj1 * 128);
            uint4 r2 = *(const uint4*)(hbase + (size_t)sj2 * 128);
            uint4 r3 = *(const uint4*)(hbase + (size_t)sj3 * 128);
            const _Float16* h0 = (const _Float16*)&r0;
            const _Float16* h1 = (const _Float16*)&r1;
            const _Float16* h2 = (const _Float16*)&r2;
            const _Float16* h3 = (const _Float16*)&r3;
            #pragma unroll
            for (int k = 0; k < 8; ++k) acc[k] += ws0 * (float)h0[k];
            #pragma unroll
            for (int k = 0; k < 8; ++k) acc[k] += ws1 * (float)h1[k];
            #pragma unroll
            for (int k = 0; k < 8; ++k) acc[k] += ws2 * (float)h2[k];
            #pragma unroll
            for (int k = 0; k < 8; ++k) acc[k] += ws3 * (float)h3[k];
            dsum += (ws0 + ws1) + (ws2 + ws3);
        }
        for (; jj + 2 <= iters; jj += 2) {
            int sl0 = hb + (jj << 1) + q;
            int sj0 = __shfl(s, sl0), sj1 = __shfl(s, sl0 + 2);
            float w00 = __shfl(w0, sl0),     w10 = __shfl(w1, sl0);
            float w01 = __shfl(w0, sl0 + 2), w11 = __shfl(w1, sl0 + 2);
            float ws0 = head0 ? w00 : w10;
            float ws1 = head0 ? w01 : w11;
            uint4 r0 = *(const uint4*)(hbase + (size_t)sj0 * 128);
            uint4 r1 = *(const uint4*)(hbase + (size_t)sj1 * 128);
            const _Float16* h0 = (const _Float16*)&r0;
            const _Float16* h1 = (const _Float16*)&r1;
            #pragma unroll
            for (int k = 0; k < 8; ++k) acc[k] += ws0 * (float)h0[k];
            #pragma unroll
            for (int k = 0; k < 8; ++k) acc[k] += ws1 * (float)h1[k];
            dsum += ws0 + ws1;
        }
        if (jj < iters) {
            int sl = hb + (jj << 1) + q;
            int   sj = __shfl(s,  sl);
            float wa = __shfl(w0, sl);
            float wb = __shfl(w1, sl);
            float ws = head0 ? wa : wb;
            uint4 raw = *(const uint4*)(hbase + (size_t)sj * 128);
            const _Float16* h = (const _Float16*)&raw;
            #pragma unroll
            for (int k = 0; k < 8; ++k) acc[k] += ws * (float)h[k];
            dsum += ws;
        }
    }

    // merge the two q-groups within each half (NOT across halves!)
    #pragma unroll
    for (int k = 0; k < 8; ++k) acc[k] += __shfl_xor(acc[k], 16);
    dsum += __shfl_xor(dsum, 16);

    float inv = 1.f / dsum;
    #pragma unroll
    for (int k = 0; k < 8; ++k) vout[k] = acc[k] * inv;
    return (q == 0) && active;
}

// ---------- phase C/D: fused aggregate(64 nodes) + next-layer GEMM ----------
__device__ void agg_gemm_tile(int tile,
        const _Float16* Hin, const float* alsrcL, const float* aldstL,
        const float* biasL, const _Float16* prev, _Float16* Res,
        const _Float16* WhT, const float* a_src, const float* a_dst,
        _Float16* Hout, float* alsrcO, float* aldstO,
        const MegaParams& P, char* smem) {
    typedef _Float16 (*AsT)[136];
    AsT As = (AsT)smem;
    const int t = threadIdx.x;
    const int lane = t & 63, w = t >> 6;
    const int block_row = tile * 64;
    const int half = lane >> 5, hl = lane & 31, p = hl & 15;

    for (int j = 0; j < 8; ++j) {
        int node = block_row + w * 16 + j * 2 + half;
        float v[8];
        bool valid = agg2(Hin, alsrcL, aldstL, P.offend, P.csr, node, P.N, v);
        if (valid) {
            int c0 = p * 8;
            #pragma unroll
            for (int k = 0; k < 8; ++k) v[k] += biasL[c0 + k];
            if (prev) {
                half8 pv = *(const half8*)(prev + (size_t)node * 128 + c0);
                #pragma unroll
                for (int k = 0; k < 8; ++k) v[k] += (float)pv[k];
            }
            #pragma unroll
            for (int k = 0; k < 8; ++k) v[k] = v[k] > 0.f ? v[k] : LEAK * v[k];
            half8 ov;
            #pragma unroll
            for (int k = 0; k < 8; ++k) ov[k] = (_Float16)v[k];
            *(half8*)(&As[node - block_row][c0]) = ov;
            *(half8*)(Res + (size_t)node * 128 + c0) = ov;
        }
    }
    // gemm_tile syncs before reading As (covers the agg writes above)
    gemm_tile(tile, nullptr, WhT, a_src, a_dst, Hout, alsrcO, aldstO, P.N, smem);
}

// ---------- the mega-kernel (normal launch, software grid barriers) ----------
__global__ __launch_bounds__(256, 4) void k_mega(MegaParams P) {
    __shared__ __align__(16) char smem[18448];
    const int G = (int)gridDim.x;
    const int bid = (int)blockIdx.x;

    // Phase A: edge binning + W transpose
    for (int it = bid; it < P.eb + 12; it += G) {
        if (it < P.eb) bin_chunk(it, P, smem);
        else           wtrans_tile(it - P.eb, P, smem);
    }
    gridbar(P.bars + 0);

    // Phase B: CSR finalize (NBK items) || GEMM layer 1 (gemm_blocks items)
    for (int it = bid; it < P.NBK + P.gemm_blocks; it += G) {
        if (it < P.NBK) scatter2_body(it, P, smem);
        else gemm_tile(it - P.NBK, P.x, P.w16t, P.asv[0], P.adv[0],
                       P.h16a, P.alsA, P.aldA, P.N, smem);
    }
    gridbar(P.bars + 1);

    // Phase C: fused agg layer1 (bias only) + GEMM layer2
    for (int it = bid; it < P.gemm_blocks; it += G)
        agg_gemm_tile(it, P.h16a, P.alsA, P.aldA, P.bsv[0], nullptr, P.bufA,
                      P.w16t + 16384, P.asv[1], P.adv[1],
                      P.h16b, P.alsB, P.aldB, P, smem);
    gridbar(P.bars + 2);

    // Phase D: fused agg layer2 (prev=bufA) + GEMM layer3
    for (int it = bid; it < P.gemm_blocks; it += G)
        agg_gemm_tile(it, P.h16b, P.alsB, P.aldB, P.bsv[1], P.bufA, P.bufB,
                      P.w16t + 32768, P.asv[2], P.adv[2],
                      P.h16a, P.alsA, P.aldA, P, smem);
    gridbar(P.bars + 3);

    // Phase E: agg layer3 (prev=bufB) + fused final linear -> logits
    {
        const int t = threadIdx.x;
        const int w = t >> 6, lane = t & 63;
        const int half = lane >> 5, hl = lane & 31, p = hl & 15;
        for (int grp = bid; grp < P.ngrpE; grp += G) {
            int node = grp * 8 + w * 2 + half;
            float v[8];
            bool valid = agg2(P.h16a, P.alsA, P.aldA, P.offend, P.csr, node, P.N, v);
            if (valid) {
                int c0 = p * 8;
                #pragma unroll
                for (int k = 0; k < 8; ++k) v[k] += P.bsv[2][c0 + k];
                half8 pv = *(const half8*)(P.bufB + (size_t)node * 128 + c0);
                #pragma unroll
                for (int k = 0; k < 8; ++k) v[k] += (float)pv[k];
                #pragma unroll
                for (int k = 0; k < 8; ++k) v[k] = v[k] > 0.f ? v[k] : LEAK * v[k];
                float partial = 0.f;
                #pragma unroll
                for (int k = 0; k < 8; ++k) partial += v[k] * P.lw[c0 + k];
                partial += __shfl_xor(partial, 1);
                partial += __shfl_xor(partial, 2);
                partial += __shfl_xor(partial, 4);
                partial += __shfl_xor(partial, 8);
                if (hl == 0) P.logits[node] = partial + P.lb[0];
            }
        }
    }
}

// ================= launch =================

extern "C" void kernel_launch(void* const* d_in, const int* in_sizes, int n_in,
                              void* d_out, int out_size, void* d_ws, size_t ws_size,
                              hipStream_t stream) {
    const float* x    = (const float*)d_in[0];
    const int*   edge = (const int*)d_in[1];
    const float* W[3]  = {(const float*)d_in[2], (const float*)d_in[6], (const float*)d_in[10]};
    const float* as[3] = {(const float*)d_in[3], (const float*)d_in[7], (const float*)d_in[11]};
    const float* ad[3] = {(const float*)d_in[4], (const float*)d_in[8], (const float*)d_in[12]};
    const float* bs[3] = {(const float*)d_in[5], (const float*)d_in[9], (const float*)d_in[13]};
    const float* lw = (const float*)d_in[14];
    const float* lb = (const float*)d_in[15];

    const int N    = in_sizes[0] / 128;
    const int E    = in_sizes[1] / 2;
    const int ETOT = E + N;
    const int NBK  = (N + 127) >> 7;   // requires N <= 65536 (here N = 50000)

    char* base = (char*)d_ws;
    size_t o = 0;
    auto carve = [&](size_t bytes) {
        char* p = base + o;
        o = (o + bytes + 255) & ~(size_t)255;
        return p;
    };
    int*      bars   = (int*)     carve(64);            // 4 barrier counters (256B slot)
    int*      gcnt   = (int*)     carve((size_t)NBK * 4);
    int2*     offend = (int2*)    carve((size_t)N * 8);
    unsigned* binned = (unsigned*)carve((size_t)NBK * BCAP * 4);
    int*      csr    = (int*)     carve((size_t)NBK * BCAP * 4);
    float*    alsA   = (float*)   carve((size_t)N * 2 * 4);
    float*    aldA   = (float*)   carve((size_t)N * 2 * 4);
    float*    alsB   = (float*)   carve((size_t)N * 2 * 4);
    float*    aldB   = (float*)   carve((size_t)N * 2 * 4);
    _Float16* h16a   = (_Float16*)carve((size_t)N * 128 * 2);
    _Float16* h16b   = (_Float16*)carve((size_t)N * 128 * 2);
    _Float16* bufA   = (_Float16*)carve((size_t)N * 128 * 2);
    _Float16* bufB   = (_Float16*)carve((size_t)N * 128 * 2);
    _Float16* w16t   = (_Float16*)carve((size_t)3 * 16384 * 2);
    (void)ws_size; (void)n_in; (void)out_size;

    // zero barrier counters + bucket counters in one memset (adjacent carves)
    (void)hipMemsetAsync(bars, 0, 256 + (size_t)NBK * 4, stream);

    MegaParams P;
    P.esrc = edge; P.edst = edge + E;
    P.bars = bars;
    P.gcnt = gcnt; P.binned = binned;
    P.E = E; P.ETOT = ETOT; P.NBK = NBK;
    P.eb = (ETOT + 4095) / 4096;
    P.W0 = W[0]; P.W1 = W[1]; P.W2 = W[2];
    P.w16t = w16t;
    P.offend = offend; P.csr = csr;
    P.x = x;
    for (int i = 0; i < 3; ++i) { P.asv[i] = as[i]; P.adv[i] = ad[i]; P.bsv[i] = bs[i]; }
    P.lw = lw; P.lb = lb;
    P.logits = (float*)d_out;
    P.h16a = h16a; P.h16b = h16b; P.bufA = bufA; P.bufB = bufB;
    P.alsA = alsA; P.aldA = aldA; P.alsB = alsB; P.aldB = aldB;
    P.N = N;
    P.gemm_blocks = (N + 63) / 64;
    P.ngrpE = (N + 7) / 8;

    k_mega<<<GRID_BLKS, 256, 0, stream>>>(P);
}

// Round 10
// 261.876 us; speedup vs baseline: 4.9173x; 2.4730x over previous
//
#include <hip/hip_runtime.h>
#include <hip/hip_bf16.h>
#include <hip/hip_fp16.h>

#define LEAK 0.2f
#define BCAP 4096   // edges per 128-node bucket; mean ~2176 for E/N=17, +40 sigma safe
#define NTILE 8     // src tiles per node adjacency (2MB of h16 per tile)
#define TSHIFT 13   // tile = src >> 13 ; requires N <= 65536

typedef _Float16 half8  __attribute__((ext_vector_type(8)));
typedef _Float16 half4v __attribute__((ext_vector_type(4)));
typedef float    float4v __attribute__((ext_vector_type(4)));

// ================= bucketed CSR build (fixed-capacity buckets) =================
// bucket b = dst >> 7 (128 nodes/bucket). packed word: src | (dloc<<17).

__global__ __launch_bounds__(256) void k_binscatter(const int* __restrict__ esrc,
                                                    const int* __restrict__ edst,
                                                    int* __restrict__ gcnt,
                                                    unsigned int* __restrict__ binned,
                                                    int E, int ETOT, int NBK, int eb,
                                                    const float* __restrict__ W0,
                                                    const float* __restrict__ W1,
                                                    const float* __restrict__ W2,
                                                    _Float16* __restrict__ w16t) {
    int t = threadIdx.x;
    if (blockIdx.x >= eb) {
        // ---- W transpose part: 12 blocks, 3 matrices x 4 (64x64) tiles ----
        __shared__ _Float16 tile[64][68];
        int bb = blockIdx.x - eb;
        int m = bb >> 2;
        int ti = (bb >> 1) & 1, tj = bb & 1;
        const float* src = (m == 0) ? W0 : (m == 1 ? W1 : W2);
        _Float16* dst = w16t + m * 16384;
        for (int idx = t; idx < 4096; idx += 256) {
            int r = idx >> 6, c = idx & 63;
            tile[r][c] = (_Float16)src[(ti * 64 + r) * 128 + tj * 64 + c];
        }
        __syncthreads();
        for (int idx = t; idx < 4096; idx += 256) {
            int c = idx >> 6, r = idx & 63;
            dst[(tj * 64 + c) * 128 + ti * 64 + r] = tile[r][c];
        }
        return;
    }
    __shared__ int lh[512];
    __shared__ int lbase[512];
    for (int b = t; b < NBK; b += 256) lh[b] = 0;
    __syncthreads();
    int base = blockIdx.x * 4096;
    unsigned int word[16]; int bb[16], rk[16];
    #pragma unroll
    for (int u = 0; u < 16; ++u) {
        int e = base + u * 256 + t;
        bb[u] = -1;
        if (e < ETOT) {
            int s, d;
            if (e < E) { s = esrc[e]; d = edst[e]; } else { s = d = e - E; }
            int b = d >> 7;
            bb[u] = b;
            rk[u] = atomicAdd(&lh[b], 1);
            word[u] = (unsigned int)s | ((unsigned int)(d & 127) << 17);
        }
    }
    __syncthreads();
    for (int b = t; b < NBK; b += 256) {
        int c = lh[b];
        lbase[b] = c ? atomicAdd(&gcnt[b], c) : 0;
    }
    __syncthreads();
    #pragma unroll
    for (int u = 0; u < 16; ++u)
        if (bb[u] >= 0)
            binned[(size_t)bb[u] * BCAP + lbase[bb[u]] + rk[u]] = word[u];
}

// per-bucket: (node,srcTile) histogram + LDS scan -> offend[] + scatter into
// bucket-strided csr, each node's adjacency grouped by ascending src tile.
__device__ void scatter2_body(int b, const unsigned int* __restrict__ binned,
                              const int* __restrict__ gcnt,
                              int2* __restrict__ offend,
                              int* __restrict__ csr, int N) {
    __shared__ int deg[128 * NTILE];   // deg[node*NTILE + tile]
    __shared__ int lcur[128 * NTILE];
    __shared__ int wt[2];
    int t = threadIdx.x;
    int n0 = b << 7;
    for (int i = t; i < 128 * NTILE; i += 256) deg[i] = 0;
    __syncthreads();
    int beg = b * BCAP, end = beg + gcnt[b];
    for (int i = beg + t; i < end; i += 256) {
        unsigned int u = binned[i];
        atomicAdd(&deg[(u >> 17) * NTILE + ((u & 0x1FFFF) >> TSHIFT)], 1);
    }
    __syncthreads();
    int v = 0, x = 0;
    if (t < 128) {
        #pragma unroll
        for (int k = 0; k < NTILE; ++k) v += deg[t * NTILE + k];
        x = v;
        int lane = t & 63;
        #pragma unroll
        for (int o = 1; o < 64; o <<= 1) {
            int y = __shfl_up(x, o);
            if (lane >= o) x += y;
        }
        if (lane == 63) wt[t >> 6] = x;
    }
    __syncthreads();
    if (t < 128) {
        int excl = x - v + ((t >= 64) ? wt[0] : 0) + beg;
        int run = excl;
        #pragma unroll
        for (int k = 0; k < NTILE; ++k) {
            lcur[t * NTILE + k] = run;
            run += deg[t * NTILE + k];
        }
        int node = n0 + t;
        if (node < N) offend[node] = make_int2(excl, excl + v);
    }
    __syncthreads();
    for (int i = beg + t; i < end; i += 256) {
        unsigned int u = binned[i];
        int pos = atomicAdd(&lcur[(u >> 17) * NTILE + ((u & 0x1FFFF) >> TSHIFT)], 1);
        csr[pos] = (int)(u & 0x1FFFF);
    }
}

// ================= MFMA fp16 GEMM + fused attention logits (layer 1) =========
// 16x16x32_f16 lane maps (m89-verified):
//   A[m][k]: m=lane&15, k=(lane>>4)*8+j ; B[k][n]: n=lane&15, k=(lane>>4)*8+j
//   C/D[r][c]: c=lane&15, r=(lane>>4)*4+reg
// Blocks < csr_nb run the CSR-finalize (scatter2) body, overlapping the GEMM.

__global__ __launch_bounds__(256) void k_gemm_mfma(const void* __restrict__ Xv, int xfp16,
                                                   const _Float16* __restrict__ WhT,
                                                   const float* __restrict__ a_src,
                                                   const float* __restrict__ a_dst,
                                                   _Float16* __restrict__ Hout,
                                                   float* __restrict__ alsrc,
                                                   float* __restrict__ aldst, int N,
                                                   int csr_nb,
                                                   const unsigned int* __restrict__ binned,
                                                   const int* __restrict__ gcnt,
                                                   int2* __restrict__ offend,
                                                   int* __restrict__ csr) {
    if ((int)blockIdx.x < csr_nb) {
        scatter2_body((int)blockIdx.x, binned, gcnt, offend, csr, N);
        return;
    }
    __shared__ _Float16 As[64][136];   // +8 pad -> 2-way bank aliasing only (free)
    __shared__ float sS[64][2];
    __shared__ float sD[64][2];
    const int t = threadIdx.x;
    const int lane = t & 63, w = t >> 6;
    const int block_row = ((int)blockIdx.x - csr_nb) * 64;

    if (t < 128) { sS[t >> 1][t & 1] = 0.f; sD[t >> 1][t & 1] = 0.f; }

    if (xfp16) {
        const _Float16* Xh = (const _Float16*)Xv;
        #pragma unroll
        for (int it = 0; it < 4; ++it) {
            int i = t + 256 * it;
            int row = i >> 4, c8 = i & 15;
            int gr = block_row + row;
            half8 hv = (half8){0,0,0,0,0,0,0,0};
            if (gr < N) hv = *(const half8*)(Xh + (size_t)gr * 128 + c8 * 8);
            *(half8*)(&As[row][c8 * 8]) = hv;
        }
    } else {
        const float* X = (const float*)Xv;
        #pragma unroll
        for (int it = 0; it < 8; ++it) {
            int i = t + 256 * it;
            int row = i >> 5, c4 = i & 31;
            int gr = block_row + row;
            float4 xv = make_float4(0.f, 0.f, 0.f, 0.f);
            if (gr < N) xv = *(const float4*)(X + (size_t)gr * 128 + c4 * 4);
            half4v hv;
            hv[0] = (_Float16)xv.x; hv[1] = (_Float16)xv.y;
            hv[2] = (_Float16)xv.z; hv[3] = (_Float16)xv.w;
            *(half4v*)(&As[row][c4 * 4]) = hv;
        }
    }

    const int l15 = lane & 15, kq = (lane >> 4) * 8;
    half8 bf[2][4];
    #pragma unroll
    for (int ntl = 0; ntl < 2; ++ntl) {
        int n0 = (w * 2 + ntl) * 16 + l15;
        #pragma unroll
        for (int kt = 0; kt < 4; ++kt)
            bf[ntl][kt] = *(const half8*)(WhT + (size_t)n0 * 128 + kt * 32 + kq);
    }
    __syncthreads();

    float4v acc[4][2];
    #pragma unroll
    for (int mt = 0; mt < 4; ++mt)
        #pragma unroll
        for (int ntl = 0; ntl < 2; ++ntl)
            acc[mt][ntl] = (float4v){0.f, 0.f, 0.f, 0.f};

    #pragma unroll
    for (int kt = 0; kt < 4; ++kt) {
        half8 a[4];
        #pragma unroll
        for (int mt = 0; mt < 4; ++mt)
            a[mt] = *(const half8*)(&As[mt * 16 + l15][kt * 32 + kq]);
        #pragma unroll
        for (int mt = 0; mt < 4; ++mt)
            #pragma unroll
            for (int ntl = 0; ntl < 2; ++ntl)
                acc[mt][ntl] = __builtin_amdgcn_mfma_f32_16x16x32_f16(
                    a[mt], bf[ntl][kt], acc[mt][ntl], 0, 0, 0);
    }

    #pragma unroll
    for (int mt = 0; mt < 4; ++mt) {
        int r0 = block_row + mt * 16 + (lane >> 4) * 4;
        #pragma unroll
        for (int ntl = 0; ntl < 2; ++ntl) {
            int col = (w * 2 + ntl) * 16 + l15;
            #pragma unroll
            for (int reg = 0; reg < 4; ++reg) {
                int r = r0 + reg;
                if (r < N) Hout[(size_t)r * 128 + col] = (_Float16)acc[mt][ntl][reg];
            }
        }
    }

    // fused attention logits: wave covers cols [w*32, w*32+32) -> head = w>>1
    {
        int c0 = w * 32 + l15, c1 = c0 + 16;
        float as0 = a_src[c0], as1 = a_src[c1];
        float ad0 = a_dst[c0], ad1 = a_dst[c1];
        int head = w >> 1;
        #pragma unroll
        for (int mt = 0; mt < 4; ++mt) {
            #pragma unroll
            for (int reg = 0; reg < 4; ++reg) {
                float ps = (float)acc[mt][0][reg] * as0 + (float)acc[mt][1][reg] * as1;
                float pd = (float)acc[mt][0][reg] * ad0 + (float)acc[mt][1][reg] * ad1;
                #pragma unroll
                for (int o = 1; o < 16; o <<= 1) {
                    ps += __shfl_xor(ps, o);
                    pd += __shfl_xor(pd, o);
                }
                if (l15 == 0) {
                    int row = mt * 16 + (lane >> 4) * 4 + reg;
                    atomicAdd(&sS[row][head], ps);
                    atomicAdd(&sD[row][head], pd);
                }
            }
        }
    }
    __syncthreads();
    if (t < 128) {
        int row = t >> 1, head = t & 1;
        int gr = block_row + row;
        if (gr < N) {
            alsrc[gr * 2 + head] = sS[row][head];
            aldst[gr * 2 + head] = sD[row][head];
        }
    }
}

// ================= FUSED aggregate_l + gemm_(l+1), 32-ROW TILES =================
// R4 ran this with 64-row tiles = 782 blocks ~= 3.0 blocks/CU (grid-limited,
// OccupancyPercent 26.8). 32-row tiles double the block count (1563 ~= 6.1/CU)
// -> ~2x resident gather waves during the latency-bound aggregate phase, and
// halve each wave's sequential node count (4 j-passes). MFMA total unchanged.
// Phase A: 4 waves x 4 passes x 2 nodes/wave aggregate 32 dst nodes into LDS
// As + residual Res. Phase B: 32x128 MFMA GEMM of layer l+1 from As.
// mode: 0 = bias only (layer1 agg); 1 = bias + prev residual (layer2 agg).

__global__ __launch_bounds__(256) void k_agg_gemm(
        const _Float16* __restrict__ H16in,  // layer-l gather table [N][128]
        const float* __restrict__ alsrcL,    // layer-l attention logits
        const float* __restrict__ aldstL,
        const int2* __restrict__ offend,
        const int* __restrict__ csr,
        const float* __restrict__ biasL,     // layer-l bias
        const _Float16* __restrict__ prev,   // residual in (mode 1)
        _Float16* __restrict__ Res,          // residual out (activated agg)
        const _Float16* __restrict__ WhT,    // layer-(l+1) weight, transposed fp16
        const float* __restrict__ a_src,     // layer-(l+1)
        const float* __restrict__ a_dst,
        _Float16* __restrict__ Hout,         // layer-(l+1) h16
        float* __restrict__ alsrcO,
        float* __restrict__ aldstO,
        int N, int mode) {
    __shared__ _Float16 As[32][136];
    __shared__ float sS[32][2];
    __shared__ float sD[32][2];
    const int t = threadIdx.x;
    const int lane = t & 63, w = t >> 6;
    const int block_row = (int)blockIdx.x * 32;

    if (t < 64) { sS[t >> 1][t & 1] = 0.f; sD[t >> 1][t & 1] = 0.f; }

    // ---------------- phase A: aggregate 32 nodes ----------------
    const int half = lane >> 5;
    const int hl = lane & 31;
    const int p = hl & 15;
    const int q = hl >> 4;
    const bool head0 = p < 8;
    const _Float16* hbase = H16in + p * 8;
    const int hb = half << 5;

    for (int j = 0; j < 4; ++j) {
        int node = block_row + w * 8 + j * 2 + half;
        bool active = node < N;
        int nodeC = active ? node : (N - 1);
        int2 oe = offend[nodeC];
        int beg = oe.x;
        int end = active ? oe.y : beg;
        float2 adv = *(const float2*)(aldstL + (size_t)nodeC * 2);
        float ad0 = adv.x, ad1 = adv.y;

        float acc[8];
        #pragma unroll
        for (int k = 0; k < 8; ++k) acc[k] = 0.f;
        float dsum = 0.f;

        for (int base = beg; base < end; base += 32) {
            int i = base + hl;
            int s = 0; float w0 = 0.f, w1 = 0.f;
            if (i < end) {
                s = csr[i];
                float2 al = *(const float2*)(&alsrcL[s * 2]);
                float e0 = al.x + ad0; e0 = e0 > 0.f ? e0 : LEAK * e0;
                float e1 = al.y + ad1; e1 = e1 > 0.f ? e1 : LEAK * e1;
                w0 = __expf(e0); w1 = __expf(e1);
            }
            int cnt = min(32, end - base);
            int iters = (cnt + 1) >> 1;
            int jj = 0;
            for (; jj + 4 <= iters; jj += 4) {
                int sl0 = hb + (jj << 1) + q;
                int sj0 = __shfl(s, sl0), sj1 = __shfl(s, sl0 + 2);
                int sj2 = __shfl(s, sl0 + 4), sj3 = __shfl(s, sl0 + 6);
                float w00 = __shfl(w0, sl0),     w10 = __shfl(w1, sl0);
                float w01 = __shfl(w0, sl0 + 2), w11 = __shfl(w1, sl0 + 2);
                float w02 = __shfl(w0, sl0 + 4), w12 = __shfl(w1, sl0 + 4);
                float w03 = __shfl(w0, sl0 + 6), w13 = __shfl(w1, sl0 + 6);
                float ws0 = head0 ? w00 : w10;
                float ws1 = head0 ? w01 : w11;
                float ws2 = head0 ? w02 : w12;
                float ws3 = head0 ? w03 : w13;
                uint4 r0 = *(const uint4*)(hbase + (size_t)sj0 * 128);
                uint4 r1 = *(const uint4*)(hbase + (size_t)sj1 * 128);
                uint4 r2 = *(const uint4*)(hbase + (size_t)sj2 * 128);
                uint4 r3 = *(const uint4*)(hbase + (size_t)sj3 * 128);
                const _Float16* h0 = (const _Float16*)&r0;
                const _Float16* h1 = (const _Float16*)&r1;
                const _Float16* h2 = (const _Float16*)&r2;
                const _Float16* h3 = (const _Float16*)&r3;
                #pragma unroll
                for (int k = 0; k < 8; ++k) acc[k] += ws0 * (float)h0[k];
                #pragma unroll
                for (int k = 0; k < 8; ++k) acc[k] += ws1 * (float)h1[k];
                #pragma unroll
                for (int k = 0; k < 8; ++k) acc[k] += ws2 * (float)h2[k];
                #pragma unroll
                for (int k = 0; k < 8; ++k) acc[k] += ws3 * (float)h3[k];
                dsum += (ws0 + ws1) + (ws2 + ws3);
            }
            for (; jj + 2 <= iters; jj += 2) {
                int sl0 = hb + (jj << 1) + q;
                int sj0 = __shfl(s, sl0), sj1 = __shfl(s, sl0 + 2);
                float w00 = __shfl(w0, sl0),     w10 = __shfl(w1, sl0);
                float w01 = __shfl(w0, sl0 + 2), w11 = __shfl(w1, sl0 + 2);
                float ws0 = head0 ? w00 : w10;
                float ws1 = head0 ? w01 : w11;
                uint4 r0 = *(const uint4*)(hbase + (size_t)sj0 * 128);
                uint4 r1 = *(const uint4*)(hbase + (size_t)sj1 * 128);
                const _Float16* h0 = (const _Float16*)&r0;
                const _Float16* h1 = (const _Float16*)&r1;
                #pragma unroll
                for (int k = 0; k < 8; ++k) acc[k] += ws0 * (float)h0[k];
                #pragma unroll
                for (int k = 0; k < 8; ++k) acc[k] += ws1 * (float)h1[k];
                dsum += ws0 + ws1;
            }
            if (jj < iters) {
                int sl = hb + (jj << 1) + q;
                int   sj = __shfl(s,  sl);
                float wa = __shfl(w0, sl);
                float wb = __shfl(w1, sl);
                float ws = head0 ? wa : wb;
                uint4 raw = *(const uint4*)(hbase + (size_t)sj * 128);
                const _Float16* h = (const _Float16*)&raw;
                #pragma unroll
                for (int k = 0; k < 8; ++k) acc[k] += ws * (float)h[k];
                dsum += ws;
            }
        }

        // merge the two q-groups within each half (NOT across halves!)
        #pragma unroll
        for (int k = 0; k < 8; ++k) acc[k] += __shfl_xor(acc[k], 16);
        dsum += __shfl_xor(dsum, 16);

        if (q == 0 && active) {
            float inv = 1.f / dsum;
            int c0 = p * 8;
            float v[8];
            #pragma unroll
            for (int k = 0; k < 8; ++k) v[k] = acc[k] * inv + biasL[c0 + k];
            if (mode >= 1) {
                half8 pv = *(const half8*)(prev + (size_t)node * 128 + c0);
                #pragma unroll
                for (int k = 0; k < 8; ++k) v[k] += (float)pv[k];
            }
            #pragma unroll
            for (int k = 0; k < 8; ++k) v[k] = v[k] > 0.f ? v[k] : LEAK * v[k];
            half8 ov;
            #pragma unroll
            for (int k = 0; k < 8; ++k) ov[k] = (_Float16)v[k];
            *(half8*)(&As[node - block_row][c0]) = ov;
            *(half8*)(Res + (size_t)node * 128 + c0) = ov;
        }
    }
    __syncthreads();

    // ---------------- phase B: GEMM layer l+1 from As (32 rows) ----------------
    const int l15 = lane & 15, kq = (lane >> 4) * 8;
    half8 bf[2][4];
    #pragma unroll
    for (int ntl = 0; ntl < 2; ++ntl) {
        int n0 = (w * 2 + ntl) * 16 + l15;
        #pragma unroll
        for (int kt = 0; kt < 4; ++kt)
            bf[ntl][kt] = *(const half8*)(WhT + (size_t)n0 * 128 + kt * 32 + kq);
    }

    float4v accB[2][2];
    #pragma unroll
    for (int mt = 0; mt < 2; ++mt)
        #pragma unroll
        for (int ntl = 0; ntl < 2; ++ntl)
            accB[mt][ntl] = (float4v){0.f, 0.f, 0.f, 0.f};

    #pragma unroll
    for (int kt = 0; kt < 4; ++kt) {
        half8 a[2];
        #pragma unroll
        for (int mt = 0; mt < 2; ++mt)
            a[mt] = *(const half8*)(&As[mt * 16 + l15][kt * 32 + kq]);
        #pragma unroll
        for (int mt = 0; mt < 2; ++mt)
            #pragma unroll
            for (int ntl = 0; ntl < 2; ++ntl)
                accB[mt][ntl] = __builtin_amdgcn_mfma_f32_16x16x32_f16(
                    a[mt], bf[ntl][kt], accB[mt][ntl], 0, 0, 0);
    }

    #pragma unroll
    for (int mt = 0; mt < 2; ++mt) {
        int r0 = block_row + mt * 16 + (lane >> 4) * 4;
        #pragma unroll
        for (int ntl = 0; ntl < 2; ++ntl) {
            int col = (w * 2 + ntl) * 16 + l15;
            #pragma unroll
            for (int reg = 0; reg < 4; ++reg) {
                int r = r0 + reg;
                if (r < N) Hout[(size_t)r * 128 + col] = (_Float16)accB[mt][ntl][reg];
            }
        }
    }

    // fused attention logits for layer l+1
    {
        int c0 = w * 32 + l15, c1 = c0 + 16;
        float as0 = a_src[c0], as1 = a_src[c1];
        float ad0 = a_dst[c0], ad1 = a_dst[c1];
        int head = w >> 1;
        #pragma unroll
        for (int mt = 0; mt < 2; ++mt) {
            #pragma unroll
            for (int reg = 0; reg < 4; ++reg) {
                float ps = (float)accB[mt][0][reg] * as0 + (float)accB[mt][1][reg] * as1;
                float pd = (float)accB[mt][0][reg] * ad0 + (float)accB[mt][1][reg] * ad1;
                #pragma unroll
                for (int o = 1; o < 16; o <<= 1) {
                    ps += __shfl_xor(ps, o);
                    pd += __shfl_xor(pd, o);
                }
                if (l15 == 0) {
                    int row = mt * 16 + (lane >> 4) * 4 + reg;
                    atomicAdd(&sS[row][head], ps);
                    atomicAdd(&sD[row][head], pd);
                }
            }
        }
    }
    __syncthreads();
    if (t < 64) {
        int row = t >> 1, head = t & 1;
        int gr = block_row + row;
        if (gr < N) {
            alsrcO[gr * 2 + head] = sS[row][head];
            aldstO[gr * 2 + head] = sD[row][head];
        }
    }
}

// ================= standalone softmax-aggregate (layer 3, fused linear) ======
// Round-2 register-gather form: 2 nodes/wave64, 4 waves/block, unroll-4 MLP.
// mode: 0 bias->Out ; 1 bias+prev->Out ; 2 bias+prev, fused lin dot -> logits

__global__ __launch_bounds__(256) void k_aggregate(
        const _Float16* __restrict__ H16,   // [N][128] fp16
        const float* __restrict__ alsrc,
        const float* __restrict__ aldst,
        const int2* __restrict__ offend,
        const int* __restrict__ csr,
        const float* __restrict__ bias,
        const _Float16* __restrict__ prev,  // fp16 residual input
        _Float16* __restrict__ Out,         // fp16 activation output
        const float* __restrict__ lw, const float* __restrict__ lb,
        float* __restrict__ logits, int N, int mode) {
    int wglobal = (int)((blockIdx.x * 256 + threadIdx.x) >> 6);
    int lane = threadIdx.x & 63;
    if (wglobal * 2 >= N) return;
    int half = lane >> 5;
    int hl = lane & 31;
    int node = wglobal * 2 + half;
    bool active = node < N;
    int nodeC = active ? node : (N - 1);
    int2 oe = offend[nodeC];
    int beg = oe.x;
    int end = active ? oe.y : beg;
    float2 adv = *(const float2*)(aldst + (size_t)nodeC * 2);
    float ad0 = adv.x, ad1 = adv.y;

    int p = hl & 15;
    int q = hl >> 4;
    bool head0 = p < 8;
    const _Float16* hbase = H16 + p * 8;
    int hb = half << 5;

    float acc[8];
    #pragma unroll
    for (int k = 0; k < 8; ++k) acc[k] = 0.f;
    float dsum = 0.f;

    for (int base = beg; base < end; base += 32) {
        int i = base + hl;
        int s = 0; float w0 = 0.f, w1 = 0.f;
        if (i < end) {
            s = csr[i];
            float2 al = *(const float2*)(&alsrc[s * 2]);
            float e0 = al.x + ad0; e0 = e0 > 0.f ? e0 : LEAK * e0;
            float e1 = al.y + ad1; e1 = e1 > 0.f ? e1 : LEAK * e1;
            w0 = __expf(e0); w1 = __expf(e1);
        }
        int cnt = min(32, end - base);
        int iters = (cnt + 1) >> 1;
        int jj = 0;
        for (; jj + 4 <= iters; jj += 4) {
            int sl0 = hb + (jj << 1) + q;
            int sj0 = __shfl(s, sl0), sj1 = __shfl(s, sl0 + 2);
            int sj2 = __shfl(s, sl0 + 4), sj3 = __shfl(s, sl0 + 6);
            float w00 = __shfl(w0, sl0),     w10 = __shfl(w1, sl0);
            float w01 = __shfl(w0, sl0 + 2), w11 = __shfl(w1, sl0 + 2);
            float w02 = __shfl(w0, sl0 + 4), w12 = __shfl(w1, sl0 + 4);
            float w03 = __shfl(w0, sl0 + 6), w13 = __shfl(w1, sl0 + 6);
            float ws0 = head0 ? w00 : w10;
            float ws1 = head0 ? w01 : w11;
            float ws2 = head0 ? w02 : w12;
            float ws3 = head0 ? w03 : w13;
            uint4 r0 = *(const uint4*)(hbase + (size_t)sj0 * 128);
            uint4 r1 = *(const uint4*)(hbase + (size_t)sj1 * 128);
            uint4 r2 = *(const uint4*)(hbase + (size_t)sj2 * 128);
            uint4 r3 = *(const uint4*)(hbase + (size_t)sj3 * 128);
            const _Float16* h0 = (const _Float16*)&r0;
            const _Float16* h1 = (const _Float16*)&r1;
            const _Float16* h2 = (const _Float16*)&r2;
            const _Float16* h3 = (const _Float16*)&r3;
            #pragma unroll
            for (int k = 0; k < 8; ++k) acc[k] += ws0 * (float)h0[k];
            #pragma unroll
            for (int k = 0; k < 8; ++k) acc[k] += ws1 * (float)h1[k];
            #pragma unroll
            for (int k = 0; k < 8; ++k) acc[k] += ws2 * (float)h2[k];
            #pragma unroll
            for (int k = 0; k < 8; ++k) acc[k] += ws3 * (float)h3[k];
            dsum += (ws0 + ws1) + (ws2 + ws3);
        }
        for (; jj + 2 <= iters; jj += 2) {
            int sl0 = hb + (jj << 1) + q;
            int sj0 = __shfl(s, sl0), sj1 = __shfl(s, sl0 + 2);
            float w00 = __shfl(w0, sl0),     w10 = __shfl(w1, sl0);
            float w01 = __shfl(w0, sl0 + 2), w11 = __shfl(w1, sl0 + 2);
            float ws0 = head0 ? w00 : w10;
            float ws1 = head0 ? w01 : w11;
            uint4 r0 = *(const uint4*)(hbase + (size_t)sj0 * 128);
            uint4 r1 = *(const uint4*)(hbase + (size_t)sj1 * 128);
            const _Float16* h0 = (const _Float16*)&r0;
            const _Float16* h1 = (const _Float16*)&r1;
            #pragma unroll
            for (int k = 0; k < 8; ++k) acc[k] += ws0 * (float)h0[k];
            #pragma unroll
            for (int k = 0; k < 8; ++k) acc[k] += ws1 * (float)h1[k];
            dsum += ws0 + ws1;
        }
        if (jj < iters) {
            int sl = hb + (jj << 1) + q;
            int   sj = __shfl(s,  sl);
            float wa = __shfl(w0, sl);
            float wb = __shfl(w1, sl);
            float ws = head0 ? wa : wb;
            uint4 raw = *(const uint4*)(hbase + (size_t)sj * 128);
            const _Float16* h = (const _Float16*)&raw;
            #pragma unroll
            for (int k = 0; k < 8; ++k) acc[k] += ws * (float)h[k];
            dsum += ws;
        }
    }

    // merge the two q-groups within each half (NOT across halves!)
    #pragma unroll
    for (int k = 0; k < 8; ++k) acc[k] += __shfl_xor(acc[k], 16);
    dsum += __shfl_xor(dsum, 16);

    if (q == 0 && active) {
        float inv = 1.f / dsum;
        int c0 = p * 8;
        float v[8];
        #pragma unroll
        for (int k = 0; k < 8; ++k) v[k] = acc[k] * inv + bias[c0 + k];
        if (mode >= 1) {
            half8 pv = *(const half8*)(prev + (size_t)node * 128 + c0);
            #pragma unroll
            for (int k = 0; k < 8; ++k) v[k] += (float)pv[k];
        }
        #pragma unroll
        for (int k = 0; k < 8; ++k) v[k] = v[k] > 0.f ? v[k] : LEAK * v[k];
        if (mode == 2) {
            float partial = 0.f;
            #pragma unroll
            for (int k = 0; k < 8; ++k) partial += v[k] * lw[c0 + k];
            partial += __shfl_xor(partial, 1);
            partial += __shfl_xor(partial, 2);
            partial += __shfl_xor(partial, 4);
            partial += __shfl_xor(partial, 8);
            if (hl == 0) logits[node] = partial + lb[0];
        } else {
            half8 ov;
            #pragma unroll
            for (int k = 0; k < 8; ++k) ov[k] = (_Float16)v[k];
            *(half8*)(Out + (size_t)node * 128 + c0) = ov;
        }
    }
}

// ================= launch =================

extern "C" void kernel_launch(void* const* d_in, const int* in_sizes, int n_in,
                              void* d_out, int out_size, void* d_ws, size_t ws_size,
                              hipStream_t stream) {
    const float* x    = (const float*)d_in[0];
    const int*   edge = (const int*)d_in[1];
    const float* W[3]  = {(const float*)d_in[2], (const float*)d_in[6], (const float*)d_in[10]};
    const float* as[3] = {(const float*)d_in[3], (const float*)d_in[7], (const float*)d_in[11]};
    const float* ad[3] = {(const float*)d_in[4], (const float*)d_in[8], (const float*)d_in[12]};
    const float* bs[3] = {(const float*)d_in[5], (const float*)d_in[9], (const float*)d_in[13]};
    const float* lw = (const float*)d_in[14];
    const float* lb = (const float*)d_in[15];

    const int N    = in_sizes[0] / 128;
    const int E    = in_sizes[1] / 2;
    const int ETOT = E + N;
    const int NBK  = (N + 127) >> 7;   // requires N <= 65536 (here N = 50000)

    char* base = (char*)d_ws;
    size_t o = 0;
    auto carve = [&](size_t bytes) {
        char* p = base + o;
        o = (o + bytes + 255) & ~(size_t)255;
        return p;
    };
    int2*     offend = (int2*)    carve((size_t)N * 8);
    int*      gcnt   = (int*)     carve((size_t)NBK * 4);
    unsigned* binned = (unsigned*)carve((size_t)NBK * BCAP * 4);
    int*      csr    = (int*)     carve((size_t)NBK * BCAP * 4);
    float*    alsA   = (float*)   carve((size_t)N * 2 * 4);
    float*    aldA   = (float*)   carve((size_t)N * 2 * 4);
    float*    alsB   = (float*)   carve((size_t)N * 2 * 4);
    float*    aldB   = (float*)   carve((size_t)N * 2 * 4);
    _Float16* h16a   = (_Float16*)carve((size_t)N * 128 * 2);
    _Float16* h16b   = (_Float16*)carve((size_t)N * 128 * 2);
    _Float16* bufA   = (_Float16*)carve((size_t)N * 128 * 2);
    _Float16* bufB   = (_Float16*)carve((size_t)N * 128 * 2);
    _Float16* w16t   = (_Float16*)carve((size_t)3 * 16384 * 2);
    (void)ws_size; (void)n_in; (void)out_size;

    const int* esrc = edge;
    const int* edst = edge + E;

    int eb = (ETOT + 4095) / 4096;

    (void)hipMemsetAsync(gcnt, 0, (size_t)NBK * 4, stream);

    // fused binning + W transpose
    k_binscatter<<<eb + 12, 256, 0, stream>>>(esrc, edst, gcnt, binned, E, ETOT, NBK, eb,
                                              W[0], W[1], W[2], w16t);

    int gemm_blocks = (N + 63) / 64;
    int agm_blocks  = (N + 31) / 32;   // 32-row fused agg+gemm tiles
    int agg_blocks  = (N + 7) / 8;     // 2 nodes per wave, 4 waves per block

    // layer 1 GEMM (fp32 input) — CSR finalize fused as the LEADING blocks so
    // it overlaps the GEMM (both only depend on k_binscatter).
    k_gemm_mfma<<<NBK + gemm_blocks, 256, 0, stream>>>(x, 0, w16t, as[0], ad[0], h16a,
                                                       alsA, aldA, N, NBK,
                                                       binned, gcnt, offend, csr);
    // fused: aggregate layer1 (mode 0) + GEMM layer2  -> h16b, alsB/aldB, bufA
    k_agg_gemm<<<agm_blocks, 256, 0, stream>>>(h16a, alsA, aldA, offend, csr,
                                               bs[0], nullptr, bufA,
                                               w16t + 16384, as[1], ad[1],
                                               h16b, alsB, aldB, N, 0);
    // fused: aggregate layer2 (mode 1, prev=bufA) + GEMM layer3 -> h16a, alsA/aldA, bufB
    k_agg_gemm<<<agm_blocks, 256, 0, stream>>>(h16b, alsB, aldB, offend, csr,
                                               bs[1], bufA, bufB,
                                               w16t + 32768, as[2], ad[2],
                                               h16a, alsA, aldA, N, 1);
    // aggregate layer3 (mode 2, prev=bufB) + fused final linear -> logits
    k_aggregate<<<agg_blocks, 256, 0, stream>>>(h16a, alsA, aldA, offend, csr,
                                                bs[2], bufB, nullptr, lw, lb,
                                                (float*)d_out, N, 2);
}